// Round 1
// baseline (686.579 us; speedup 1.0000x reference)
//
#include <hip/hip_runtime.h>
#include <math.h>

#define NN 50000
#define NE 800000
#define ET (NE + NN)          // edges + self loops
#define F1 256                // HEADS*HID
#define NEG 0.2f
#define BN_EPS 1e-5f

typedef __attribute__((ext_vector_type(8))) short short8;
typedef __attribute__((ext_vector_type(4))) float float4v;

__device__ __forceinline__ float bf2f(unsigned short u) {
    unsigned int x = ((unsigned int)u) << 16;
    return __builtin_bit_cast(float, x);
}
__device__ __forceinline__ unsigned short f2bf(float f) {
    unsigned int x = __builtin_bit_cast(unsigned int, f);
    unsigned int lsb = (x >> 16) & 1u;
    x += 0x7fffu + lsb;
    return (unsigned short)(x >> 16);
}
__device__ __forceinline__ float lrelu(float x) { return x > 0.f ? x : NEG * x; }

// ---------------- prep kernels ----------------
__global__ void cast_f32_bf16(const float* __restrict__ in, unsigned short* __restrict__ out, int n4) {
    int i = (blockIdx.x * 256 + threadIdx.x);
    if (i < n4) {
        float4 v = ((const float4*)in)[i];
        ushort4 o;
        o.x = f2bf(v.x); o.y = f2bf(v.y); o.z = f2bf(v.z); o.w = f2bf(v.w);
        ((ushort4*)out)[i] = o;
    }
}

// W [K][Nn] f32 -> Wt [Nn][K] bf16
__global__ void transpose_w(const float* __restrict__ W, unsigned short* __restrict__ Wt, int K, int Nn) {
    int id = blockIdx.x * 256 + threadIdx.x;
    if (id < K * Nn) {
        int n = id / K, k = id - n * K;
        Wt[id] = f2bf(W[k * Nn + n]);
    }
}

// fold bias+BN: y = relu((x+b-m)*g*rsqrt(v+eps)+be) = relu(x*S + T)
__global__ void bn_prep(const float* __restrict__ b, const float* __restrict__ g,
                        const float* __restrict__ be, const float* __restrict__ m,
                        const float* __restrict__ v, float* __restrict__ S, float* __restrict__ T, int n) {
    int j = blockIdx.x * 256 + threadIdx.x;
    if (j < n) {
        float s = g[j] * rsqrtf(v[j] + BN_EPS);
        S[j] = s;
        T[j] = (b[j] - m[j]) * s + be[j];
    }
}

// ---------------- CSR build ----------------
__global__ void edge_hist(const int* __restrict__ ei, int* __restrict__ counts) {
    int e = blockIdx.x * 256 + threadIdx.x;
    if (e < ET) {
        int dst = (e < NE) ? ei[NE + e] : (e - NE);
        atomicAdd(&counts[dst], 1);
    }
}

__global__ void scan_a(const int* __restrict__ counts, int* __restrict__ rowptr, int* __restrict__ bsum) {
    __shared__ int s[256];
    int t = threadIdx.x, i = blockIdx.x * 256 + t;
    int v = (i < NN) ? counts[i] : 0;
    s[t] = v;
    __syncthreads();
    for (int off = 1; off < 256; off <<= 1) {
        int add = (t >= off) ? s[t - off] : 0;
        __syncthreads();
        s[t] += add;
        __syncthreads();
    }
    if (i < NN) rowptr[i + 1] = s[t];
    if (t == 255) bsum[blockIdx.x] = s[255];
}

__global__ void scan_b(int* __restrict__ bsum, int nb) {
    if (threadIdx.x == 0 && blockIdx.x == 0) {
        int run = 0;
        for (int b = 0; b < nb; ++b) { int t = bsum[b]; bsum[b] = run; run += t; }
    }
}

__global__ void scan_c(int* __restrict__ rowptr, const int* __restrict__ bsum) {
    int i = blockIdx.x * 256 + threadIdx.x;
    if (i < NN) rowptr[i + 1] += bsum[i >> 8];
    if (i == 0) rowptr[0] = 0;
}

__global__ void copy_cursor(const int* __restrict__ rowptr, int* __restrict__ cursor) {
    int i = blockIdx.x * 256 + threadIdx.x;
    if (i < NN) cursor[i] = rowptr[i];
}

__global__ void edge_scatter(const int* __restrict__ ei, int* __restrict__ cursor, int* __restrict__ csr) {
    int e = blockIdx.x * 256 + threadIdx.x;
    if (e < ET) {
        int src, dst;
        if (e < NE) { src = ei[e]; dst = ei[NE + e]; }
        else        { src = e - NE; dst = src; }
        int pos = atomicAdd(&cursor[dst], 1);
        csr[pos] = src;
    }
}

// ---------------- bf16 MFMA GEMM: C[M][Nn] = A[M][K] * Bt[Nn][K]^T ----------------
#define BM 128
#define BN 128
#define BK 64
#define LP 72  // BK + 8 pad (bf16 elems): row pitch 144B = 9*16B, keeps b128 reads aligned, 2-way bank max

__global__ __launch_bounds__(256) void gemm_bf16(const unsigned short* __restrict__ A,
                                                 const unsigned short* __restrict__ Bt,
                                                 unsigned short* __restrict__ C,
                                                 int M, int K, int Nn) {
    __shared__ __align__(16) unsigned short As[BM * LP];
    __shared__ __align__(16) unsigned short Bs[BN * LP];
    int tid = threadIdx.x;
    int lane = tid & 63;
    int w = tid >> 6;
    int wr = w >> 1, wc = w & 1;
    int mBase = blockIdx.x * BM;
    int nBase = blockIdx.y * BN;

    float4v acc[4][4];
    for (int i = 0; i < 4; ++i)
        for (int j = 0; j < 4; ++j)
            acc[i][j] = (float4v){0.f, 0.f, 0.f, 0.f};

    int lm = lane & 15;
    int lk = (lane >> 4) * 8;

    for (int k0 = 0; k0 < K; k0 += BK) {
        for (int p = 0; p < 4; ++p) {
            int chunk = p * 256 + tid;       // 1024 chunks of 8 elems = 128x64
            int row = chunk >> 3;
            int c8 = (chunk & 7) * 8;
            int gm = mBase + row;
            short8 va = {0, 0, 0, 0, 0, 0, 0, 0};
            if (gm < M) va = *(const short8*)(A + (size_t)gm * K + k0 + c8);
            *(short8*)(&As[row * LP + c8]) = va;
            int gn = nBase + row;            // Nn multiple of 128 here
            short8 vb = *(const short8*)(Bt + (size_t)gn * K + k0 + c8);
            *(short8*)(&Bs[row * LP + c8]) = vb;
        }
        __syncthreads();
        for (int ks = 0; ks < BK; ks += 32) {
            short8 af[4], bf[4];
            for (int i = 0; i < 4; ++i)
                af[i] = *(const short8*)(&As[(wr * 64 + i * 16 + lm) * LP + ks + lk]);
            for (int j = 0; j < 4; ++j)
                bf[j] = *(const short8*)(&Bs[(wc * 64 + j * 16 + lm) * LP + ks + lk]);
            for (int i = 0; i < 4; ++i)
                for (int j = 0; j < 4; ++j)
                    acc[i][j] = __builtin_amdgcn_mfma_f32_16x16x32_bf16(af[i], bf[j], acc[i][j], 0, 0, 0);
        }
        __syncthreads();
    }
    int lr = (lane >> 4) * 4;
    for (int i = 0; i < 4; ++i)
        for (int j = 0; j < 4; ++j) {
            int col = nBase + wc * 64 + j * 16 + lm;
            for (int r = 0; r < 4; ++r) {
                int row = mBase + wr * 64 + i * 16 + lr + r;
                if (row < M) C[(size_t)row * Nn + col] = f2bf(acc[i][j][r]);
            }
        }
}

// ---------------- s/d node coefficients, layers 1&2 (H=4, C=64) ----------------
__global__ __launch_bounds__(256) void sd12(const unsigned short* __restrict__ h,
                                            const float* __restrict__ a_s, const float* __restrict__ a_d,
                                            float* __restrict__ s_arr, float* __restrict__ d_arr) {
    int lane = threadIdx.x & 63;
    int node = blockIdx.x * 4 + (threadIdx.x >> 6);
    if (node >= NN) return;
    const unsigned short* hr = h + (size_t)node * F1;
    float sv[4], dv[4];
    for (int hh = 0; hh < 4; ++hh) {
        float v = bf2f(hr[hh * 64 + lane]);
        sv[hh] = v * a_s[hh * 64 + lane];
        dv[hh] = v * a_d[hh * 64 + lane];
    }
    for (int off = 32; off; off >>= 1)
        for (int hh = 0; hh < 4; ++hh) {
            sv[hh] += __shfl_xor(sv[hh], off);
            dv[hh] += __shfl_xor(dv[hh], off);
        }
    if (lane == 0)
        for (int hh = 0; hh < 4; ++hh) {
            s_arr[node * 4 + hh] = sv[hh];
            d_arr[node * 4 + hh] = dv[hh];
        }
}

// ---------------- fused softmax-attention aggregation, layers 1&2 ----------------
__global__ __launch_bounds__(256) void agg12(const unsigned short* __restrict__ h,
                                             const float* __restrict__ s_arr, const float* __restrict__ d_arr,
                                             const int* __restrict__ rowptr, const int* __restrict__ csr,
                                             const float* __restrict__ S, const float* __restrict__ T,
                                             unsigned short* __restrict__ out) {
    int lane = threadIdx.x & 63;
    int node = blockIdx.x * 4 + (threadIdx.x >> 6);
    if (node >= NN) return;
    int r0 = rowptr[node], r1 = rowptr[node + 1];
    float4 dv = *(const float4*)(d_arr + node * 4);
    // pass A: per-head max of leaky(s+d)
    float m0 = -1e30f, m1 = -1e30f, m2 = -1e30f, m3 = -1e30f;
    for (int base = r0; base < r1; base += 64) {
        int e = base + lane;
        if (e < r1) {
            int src = csr[e];
            float4 sv = *(const float4*)(s_arr + src * 4);
            m0 = fmaxf(m0, lrelu(sv.x + dv.x));
            m1 = fmaxf(m1, lrelu(sv.y + dv.y));
            m2 = fmaxf(m2, lrelu(sv.z + dv.z));
            m3 = fmaxf(m3, lrelu(sv.w + dv.w));
        }
    }
    for (int off = 32; off; off >>= 1) {
        m0 = fmaxf(m0, __shfl_xor(m0, off));
        m1 = fmaxf(m1, __shfl_xor(m1, off));
        m2 = fmaxf(m2, __shfl_xor(m2, off));
        m3 = fmaxf(m3, __shfl_xor(m3, off));
    }
    // pass B: weighted accumulate (lane = channel c, 4 heads)
    float a0 = 0.f, a1 = 0.f, a2 = 0.f, a3 = 0.f;
    float d0 = 0.f, d1 = 0.f, d2 = 0.f, d3 = 0.f;
    for (int e = r0; e < r1; ++e) {
        int src = csr[e];
        float4 sv = *(const float4*)(s_arr + src * 4);
        float w0 = __expf(lrelu(sv.x + dv.x) - m0);
        float w1 = __expf(lrelu(sv.y + dv.y) - m1);
        float w2 = __expf(lrelu(sv.z + dv.z) - m2);
        float w3 = __expf(lrelu(sv.w + dv.w) - m3);
        d0 += w0; d1 += w1; d2 += w2; d3 += w3;
        const unsigned short* hr = h + (size_t)src * F1 + lane;
        a0 += w0 * bf2f(hr[0]);
        a1 += w1 * bf2f(hr[64]);
        a2 += w2 * bf2f(hr[128]);
        a3 += w3 * bf2f(hr[192]);
    }
    // epilogue: normalize + bias+BN folded + relu, write bf16
    float vals[4] = {a0 / d0, a1 / d1, a2 / d2, a3 / d3};
    for (int hh = 0; hh < 4; ++hh) {
        int j = hh * 64 + lane;
        float v = vals[hh] * S[j] + T[j];
        v = fmaxf(v, 0.f);
        out[(size_t)node * F1 + j] = f2bf(v);
    }
}

// ---------------- layer-3 GEMM (N=16) + fused s3/d3 ----------------
__global__ __launch_bounds__(256) void gemm3_sd(const unsigned short* __restrict__ A, // [NN][256] bf16
                                                const float* __restrict__ W3,         // [256][16]
                                                const float* __restrict__ as3, const float* __restrict__ ad3,
                                                float* __restrict__ h3, float* __restrict__ s3, float* __restrict__ d3) {
    __shared__ __align__(16) float Ws[256 * 16];
    int tid = threadIdx.x;
    for (int p = tid; p < 1024; p += 256)
        ((float4*)Ws)[p] = ((const float4*)W3)[p];
    __syncthreads();
    int nl = tid >> 2;
    int q = tid & 3;
    int node = blockIdx.x * 64 + nl;
    float acc[16];
    for (int j = 0; j < 16; ++j) acc[j] = 0.f;
    if (node < NN) {
        const unsigned short* ar = A + (size_t)node * F1;
        for (int c = q; c < 32; c += 4) {  // 16B chunks, interleaved over 4 lanes
            short8 v8 = *(const short8*)(ar + c * 8);
            for (int u = 0; u < 8; ++u) {
                float av = bf2f((unsigned short)v8[u]);
                const float* wr = Ws + (c * 8 + u) * 16;
                float4 w0 = *(const float4*)(wr);
                float4 w1 = *(const float4*)(wr + 4);
                float4 w2 = *(const float4*)(wr + 8);
                float4 w3 = *(const float4*)(wr + 12);
                acc[0]  += av * w0.x; acc[1]  += av * w0.y; acc[2]  += av * w0.z; acc[3]  += av * w0.w;
                acc[4]  += av * w1.x; acc[5]  += av * w1.y; acc[6]  += av * w1.z; acc[7]  += av * w1.w;
                acc[8]  += av * w2.x; acc[9]  += av * w2.y; acc[10] += av * w2.z; acc[11] += av * w2.w;
                acc[12] += av * w3.x; acc[13] += av * w3.y; acc[14] += av * w3.z; acc[15] += av * w3.w;
            }
        }
    }
    for (int j = 0; j < 16; ++j) {
        acc[j] += __shfl_xor(acc[j], 1);
        acc[j] += __shfl_xor(acc[j], 2);
    }
    if (q == 0 && node < NN) {
        float sv = 0.f, dvv = 0.f;
        for (int j = 0; j < 16; ++j) {
            h3[(size_t)node * 16 + j] = acc[j];
            sv += acc[j] * as3[j];
            dvv += acc[j] * ad3[j];
        }
        s3[node] = sv;
        d3[node] = dvv;
    }
}

// ---------------- layer-3 aggregation (H=1, C=16) -> d_out ----------------
__global__ __launch_bounds__(256) void agg3(const float* __restrict__ h3, const float* __restrict__ s3,
                                            const float* __restrict__ d3, const int* __restrict__ rowptr,
                                            const int* __restrict__ csr, const float* __restrict__ b3,
                                            float* __restrict__ out) {
    int lane = threadIdx.x & 63;
    int node = blockIdx.x * 4 + (threadIdx.x >> 6);
    if (node >= NN) return;
    int r0 = rowptr[node], r1 = rowptr[node + 1];
    float dv = d3[node];
    float m = -1e30f;
    for (int base = r0; base < r1; base += 64) {
        int e = base + lane;
        if (e < r1) m = fmaxf(m, lrelu(s3[csr[e]] + dv));
    }
    for (int off = 32; off; off >>= 1) m = fmaxf(m, __shfl_xor(m, off));
    float acc = 0.f, den = 0.f;
    for (int e = r0; e < r1; ++e) {
        int src = csr[e];
        float w = __expf(lrelu(s3[src] + dv) - m);
        den += w;
        if (lane < 16) acc += w * h3[(size_t)src * 16 + lane];
    }
    if (lane < 16) out[(size_t)node * 16 + lane] = acc / den + b3[lane];
}

// ---------------- host ----------------
extern "C" void kernel_launch(void* const* d_in, const int* in_sizes, int n_in,
                              void* d_out, int out_size, void* d_ws, size_t ws_size,
                              hipStream_t stream) {
    const float* x   = (const float*)d_in[0];
    const int*   ei  = (const int*)d_in[1];
    const float* W1  = (const float*)d_in[2];
    const float* as1 = (const float*)d_in[3];
    const float* ad1 = (const float*)d_in[4];
    const float* b1  = (const float*)d_in[5];
    const float* g1  = (const float*)d_in[6];
    const float* be1 = (const float*)d_in[7];
    const float* m1  = (const float*)d_in[8];
    const float* v1  = (const float*)d_in[9];
    const float* W2  = (const float*)d_in[10];
    const float* as2 = (const float*)d_in[11];
    const float* ad2 = (const float*)d_in[12];
    const float* b2  = (const float*)d_in[13];
    const float* g2  = (const float*)d_in[14];
    const float* be2 = (const float*)d_in[15];
    const float* m2  = (const float*)d_in[16];
    const float* v2  = (const float*)d_in[17];
    const float* W3  = (const float*)d_in[18];
    const float* as3 = (const float*)d_in[19];
    const float* ad3 = (const float*)d_in[20];
    const float* b3  = (const float*)d_in[21];

    char* w = (char*)d_ws;
    size_t off = 0;
    auto alloc = [&](size_t bytes) -> void* {
        off = (off + 255) & ~(size_t)255;
        void* p = w + off;
        off += bytes;
        return p;
    };
    unsigned short* xb   = (unsigned short*)alloc((size_t)NN * 128 * 2);
    unsigned short* W1t  = (unsigned short*)alloc(256 * 128 * 2);
    unsigned short* W2t  = (unsigned short*)alloc(256 * 256 * 2);
    unsigned short* Abuf = (unsigned short*)alloc((size_t)NN * F1 * 2);  // h1 / h2
    unsigned short* Bbuf = (unsigned short*)alloc((size_t)NN * F1 * 2);  // out1 / out2
    float* h3    = (float*)alloc((size_t)NN * 16 * 4);
    float* s_arr = (float*)alloc((size_t)NN * 4 * 4);
    float* d_arr = (float*)alloc((size_t)NN * 4 * 4);
    float* s3    = (float*)alloc((size_t)NN * 4);
    float* d3    = (float*)alloc((size_t)NN * 4);
    int* counts  = (int*)alloc((size_t)NN * 4);
    int* rowptr  = (int*)alloc((size_t)(NN + 1) * 4);
    int* cursor  = (int*)alloc((size_t)NN * 4);
    int* csr     = (int*)alloc((size_t)ET * 4);
    int* bsum    = (int*)alloc(256 * 4);
    float* S1 = (float*)alloc(F1 * 4);
    float* T1 = (float*)alloc(F1 * 4);
    float* S2 = (float*)alloc(F1 * 4);
    float* T2 = (float*)alloc(F1 * 4);
    float* outp = (float*)d_out;

    int nb_scan = (NN + 255) / 256;        // 196
    int nb_edge = (ET + 255) / 256;        // 3321

    // prep
    cast_f32_bf16<<<(NN * 128 / 4 + 255) / 256, 256, 0, stream>>>(x, xb, NN * 128 / 4);
    transpose_w<<<(128 * 256 + 255) / 256, 256, 0, stream>>>(W1, W1t, 128, 256);
    transpose_w<<<(256 * 256 + 255) / 256, 256, 0, stream>>>(W2, W2t, 256, 256);
    bn_prep<<<1, 256, 0, stream>>>(b1, g1, be1, m1, v1, S1, T1, F1);
    bn_prep<<<1, 256, 0, stream>>>(b2, g2, be2, m2, v2, S2, T2, F1);

    // CSR by dst
    hipMemsetAsync(counts, 0, (size_t)NN * 4, stream);
    edge_hist<<<nb_edge, 256, 0, stream>>>(ei, counts);
    scan_a<<<nb_scan, 256, 0, stream>>>(counts, rowptr, bsum);
    scan_b<<<1, 64, 0, stream>>>(bsum, nb_scan);
    scan_c<<<nb_scan, 256, 0, stream>>>(rowptr, bsum);
    copy_cursor<<<nb_scan, 256, 0, stream>>>(rowptr, cursor);
    edge_scatter<<<nb_edge, 256, 0, stream>>>(ei, cursor, csr);

    dim3 ggrid((NN + BM - 1) / BM, F1 / BN);

    // layer 1
    gemm_bf16<<<ggrid, 256, 0, stream>>>(xb, W1t, Abuf, NN, 128, F1);
    sd12<<<(NN + 3) / 4, 256, 0, stream>>>(Abuf, as1, ad1, s_arr, d_arr);
    agg12<<<(NN + 3) / 4, 256, 0, stream>>>(Abuf, s_arr, d_arr, rowptr, csr, S1, T1, Bbuf);

    // layer 2
    gemm_bf16<<<ggrid, 256, 0, stream>>>(Bbuf, W2t, Abuf, NN, 256, F1);
    sd12<<<(NN + 3) / 4, 256, 0, stream>>>(Abuf, as2, ad2, s_arr, d_arr);
    agg12<<<(NN + 3) / 4, 256, 0, stream>>>(Abuf, s_arr, d_arr, rowptr, csr, S2, T2, Bbuf);

    // layer 3
    gemm3_sd<<<(NN + 63) / 64, 256, 0, stream>>>(Bbuf, W3, as3, ad3, h3, s3, d3);
    agg3<<<(NN + 3) / 4, 256, 0, stream>>>(h3, s3, d3, rowptr, csr, b3, outp);
}

// Round 2
// 504.516 us; speedup vs baseline: 1.3609x; 1.3609x over previous
//
#include <hip/hip_runtime.h>
#include <math.h>

#define NN 50000
#define NE 800000
#define ET (NE + NN)          // edges + self loops
#define F1 256                // HEADS*HID
#define NEG 0.2f
#define BN_EPS 1e-5f

typedef __attribute__((ext_vector_type(8))) short short8;
typedef __attribute__((ext_vector_type(4))) float float4v;
typedef __attribute__((ext_vector_type(4))) unsigned short ushort4v;

__device__ __forceinline__ float bf2f(unsigned short u) {
    unsigned int x = ((unsigned int)u) << 16;
    return __builtin_bit_cast(float, x);
}
__device__ __forceinline__ unsigned short f2bf(float f) {
    unsigned int x = __builtin_bit_cast(unsigned int, f);
    unsigned int lsb = (x >> 16) & 1u;
    x += 0x7fffu + lsb;
    return (unsigned short)(x >> 16);
}
__device__ __forceinline__ float lrelu(float x) { return x > 0.f ? x : NEG * x; }

// ---------------- prep kernels ----------------
__global__ void cast_f32_bf16(const float* __restrict__ in, unsigned short* __restrict__ out, int n4) {
    int i = (blockIdx.x * 256 + threadIdx.x);
    if (i < n4) {
        float4 v = ((const float4*)in)[i];
        ushort4 o;
        o.x = f2bf(v.x); o.y = f2bf(v.y); o.z = f2bf(v.z); o.w = f2bf(v.w);
        ((ushort4*)out)[i] = o;
    }
}

// W [K][Nn] f32 -> Wt [Nn][K] bf16
__global__ void transpose_w(const float* __restrict__ W, unsigned short* __restrict__ Wt, int K, int Nn) {
    int id = blockIdx.x * 256 + threadIdx.x;
    if (id < K * Nn) {
        int n = id / K, k = id - n * K;
        Wt[id] = f2bf(W[k * Nn + n]);
    }
}

// fold bias+BN: y = relu((x+b-m)*g*rsqrt(v+eps)+be) = relu(x*S + T)
__global__ void bn_prep(const float* __restrict__ b, const float* __restrict__ g,
                        const float* __restrict__ be, const float* __restrict__ m,
                        const float* __restrict__ v, float* __restrict__ S, float* __restrict__ T, int n) {
    int j = blockIdx.x * 256 + threadIdx.x;
    if (j < n) {
        float s = g[j] * rsqrtf(v[j] + BN_EPS);
        S[j] = s;
        T[j] = (b[j] - m[j]) * s + be[j];
    }
}

// ---------------- CSR build ----------------
__global__ void edge_hist(const int* __restrict__ ei, int* __restrict__ counts) {
    int e = blockIdx.x * 256 + threadIdx.x;
    if (e < ET) {
        int dst = (e < NE) ? ei[NE + e] : (e - NE);
        atomicAdd(&counts[dst], 1);
    }
}

__global__ void scan_a(const int* __restrict__ counts, int* __restrict__ rowptr, int* __restrict__ bsum) {
    __shared__ int s[256];
    int t = threadIdx.x, i = blockIdx.x * 256 + t;
    int v = (i < NN) ? counts[i] : 0;
    s[t] = v;
    __syncthreads();
    for (int off = 1; off < 256; off <<= 1) {
        int add = (t >= off) ? s[t - off] : 0;
        __syncthreads();
        s[t] += add;
        __syncthreads();
    }
    if (i < NN) rowptr[i + 1] = s[t];
    if (t == 255) bsum[blockIdx.x] = s[255];
}

// parallel exclusive scan over <=256 block sums (1 block, 256 thr)
__global__ void scan_b(int* __restrict__ bsum, int nb) {
    __shared__ int s[256];
    int t = threadIdx.x;
    int v = (t < nb) ? bsum[t] : 0;
    s[t] = v;
    __syncthreads();
    for (int off = 1; off < 256; off <<= 1) {
        int add = (t >= off) ? s[t - off] : 0;
        __syncthreads();
        s[t] += add;
        __syncthreads();
    }
    if (t < nb) bsum[t] = s[t] - v;  // exclusive
}

__global__ void scan_c(int* __restrict__ rowptr, const int* __restrict__ bsum) {
    int i = blockIdx.x * 256 + threadIdx.x;
    if (i < NN) rowptr[i + 1] += bsum[i >> 8];
    if (i == 0) rowptr[0] = 0;
}

__global__ void copy_cursor(const int* __restrict__ rowptr, int* __restrict__ cursor) {
    int i = blockIdx.x * 256 + threadIdx.x;
    if (i < NN) cursor[i] = rowptr[i];
}

__global__ void edge_scatter(const int* __restrict__ ei, int* __restrict__ cursor, int* __restrict__ csr) {
    int e = blockIdx.x * 256 + threadIdx.x;
    if (e < ET) {
        int src, dst;
        if (e < NE) { src = ei[e]; dst = ei[NE + e]; }
        else        { src = e - NE; dst = src; }
        int pos = atomicAdd(&cursor[dst], 1);
        csr[pos] = src;
    }
}

// ---------------- bf16 MFMA GEMM: C[M][Nn] = A[M][K] * Bt[Nn][K]^T ----------------
#define BM 128
#define BN 128
#define BK 64
#define LP 72  // BK + 8 pad

__global__ __launch_bounds__(256) void gemm_bf16(const unsigned short* __restrict__ A,
                                                 const unsigned short* __restrict__ Bt,
                                                 unsigned short* __restrict__ C,
                                                 int M, int K, int Nn) {
    __shared__ __align__(16) unsigned short As[BM * LP];
    __shared__ __align__(16) unsigned short Bs[BN * LP];
    int tid = threadIdx.x;
    int lane = tid & 63;
    int w = tid >> 6;
    int wr = w >> 1, wc = w & 1;
    int mBase = blockIdx.x * BM;
    int nBase = blockIdx.y * BN;

    float4v acc[4][4];
    for (int i = 0; i < 4; ++i)
        for (int j = 0; j < 4; ++j)
            acc[i][j] = (float4v){0.f, 0.f, 0.f, 0.f};

    int lm = lane & 15;
    int lk = (lane >> 4) * 8;

    for (int k0 = 0; k0 < K; k0 += BK) {
        for (int p = 0; p < 4; ++p) {
            int chunk = p * 256 + tid;
            int row = chunk >> 3;
            int c8 = (chunk & 7) * 8;
            int gm = mBase + row;
            short8 va = {0, 0, 0, 0, 0, 0, 0, 0};
            if (gm < M) va = *(const short8*)(A + (size_t)gm * K + k0 + c8);
            *(short8*)(&As[row * LP + c8]) = va;
            int gn = nBase + row;
            short8 vb = *(const short8*)(Bt + (size_t)gn * K + k0 + c8);
            *(short8*)(&Bs[row * LP + c8]) = vb;
        }
        __syncthreads();
        for (int ks = 0; ks < BK; ks += 32) {
            short8 af[4], bf[4];
            for (int i = 0; i < 4; ++i)
                af[i] = *(const short8*)(&As[(wr * 64 + i * 16 + lm) * LP + ks + lk]);
            for (int j = 0; j < 4; ++j)
                bf[j] = *(const short8*)(&Bs[(wc * 64 + j * 16 + lm) * LP + ks + lk]);
            for (int i = 0; i < 4; ++i)
                for (int j = 0; j < 4; ++j)
                    acc[i][j] = __builtin_amdgcn_mfma_f32_16x16x32_bf16(af[i], bf[j], acc[i][j], 0, 0, 0);
        }
        __syncthreads();
    }
    int lr = (lane >> 4) * 4;
    for (int i = 0; i < 4; ++i)
        for (int j = 0; j < 4; ++j) {
            int col = nBase + wc * 64 + j * 16 + lm;
            for (int r = 0; r < 4; ++r) {
                int row = mBase + wr * 64 + i * 16 + lr + r;
                if (row < M) C[(size_t)row * Nn + col] = f2bf(acc[i][j][r]);
            }
        }
}

// ---------------- s/d node coefficients, layers 1&2 (H=4, C=64) ----------------
__global__ __launch_bounds__(256) void sd12(const unsigned short* __restrict__ h,
                                            const float* __restrict__ a_s, const float* __restrict__ a_d,
                                            float* __restrict__ s_arr, float* __restrict__ d_arr) {
    int lane = threadIdx.x & 63;
    int node = blockIdx.x * 4 + (threadIdx.x >> 6);
    if (node >= NN) return;
    const unsigned short* hr = h + (size_t)node * F1;
    float sv[4], dv[4];
    for (int hh = 0; hh < 4; ++hh) {
        float v = bf2f(hr[hh * 64 + lane]);
        sv[hh] = v * a_s[hh * 64 + lane];
        dv[hh] = v * a_d[hh * 64 + lane];
    }
    for (int off = 32; off; off >>= 1)
        for (int hh = 0; hh < 4; ++hh) {
            sv[hh] += __shfl_xor(sv[hh], off);
            dv[hh] += __shfl_xor(dv[hh], off);
        }
    if (lane == 0)
        for (int hh = 0; hh < 4; ++hh) {
            s_arr[node * 4 + hh] = sv[hh];
            d_arr[node * 4 + hh] = dv[hh];
        }
}

// ---------------- fused softmax-attention aggregation, layers 1&2 ----------------
// one wave per dst node; per 64-edge chunk: lane e computes weights for edge e
// (staged to this wave's LDS slice), then a serial sweep where lane = 4 channels.
__global__ __launch_bounds__(256) void agg12(const unsigned short* __restrict__ h,
                                             const float* __restrict__ s_arr, const float* __restrict__ d_arr,
                                             const int* __restrict__ rowptr, const int* __restrict__ csr,
                                             const float* __restrict__ S, const float* __restrict__ T,
                                             unsigned short* __restrict__ out) {
    __shared__ float wls[4][64 * 5];   // per-wave: 64 edges x {w0,w1,w2,w3,src}
    int lane = threadIdx.x & 63;
    int wv = threadIdx.x >> 6;
    int node = blockIdx.x * 4 + wv;
    if (node >= NN) return;
    int r0 = rowptr[node], r1 = rowptr[node + 1];
    float4 dv = *(const float4*)(d_arr + node * 4);
    int head = lane >> 4;
    float* wbuf = &wls[wv][0];

    float acc0 = 0.f, acc1 = 0.f, acc2 = 0.f, acc3 = 0.f;
    float den0 = 0.f, den1 = 0.f, den2 = 0.f, den3 = 0.f;

    for (int base = r0; base < r1; base += 64) {
        int cnt = min(64, r1 - base);
        if (lane < cnt) {
            int src = csr[base + lane];
            float4 sv = *(const float4*)(s_arr + src * 4);
            float w0 = __expf(lrelu(sv.x + dv.x));
            float w1 = __expf(lrelu(sv.y + dv.y));
            float w2 = __expf(lrelu(sv.z + dv.z));
            float w3 = __expf(lrelu(sv.w + dv.w));
            den0 += w0; den1 += w1; den2 += w2; den3 += w3;
            float* wp = wbuf + lane * 5;
            wp[0] = w0; wp[1] = w1; wp[2] = w2; wp[3] = w3;
            wp[4] = __int_as_float(src);
        }
        for (int k = 0; k < cnt; ++k) {
            const float* wp = wbuf + k * 5;
            int src = __float_as_int(wp[4]);
            float wgt = wp[head];
            ushort4v hv = *(const ushort4v*)(h + (size_t)src * F1 + lane * 4);
            acc0 += wgt * bf2f(hv.x);
            acc1 += wgt * bf2f(hv.y);
            acc2 += wgt * bf2f(hv.z);
            acc3 += wgt * bf2f(hv.w);
        }
    }
    for (int off = 32; off; off >>= 1) {
        den0 += __shfl_xor(den0, off);
        den1 += __shfl_xor(den1, off);
        den2 += __shfl_xor(den2, off);
        den3 += __shfl_xor(den3, off);
    }
    float den = (head == 0) ? den0 : (head == 1) ? den1 : (head == 2) ? den2 : den3;
    float inv = 1.f / den;
    int j = lane * 4;
    float4 Sv = *(const float4*)(S + j);
    float4 Tv = *(const float4*)(T + j);
    ushort4v o;
    o.x = f2bf(fmaxf(acc0 * inv * Sv.x + Tv.x, 0.f));
    o.y = f2bf(fmaxf(acc1 * inv * Sv.y + Tv.y, 0.f));
    o.z = f2bf(fmaxf(acc2 * inv * Sv.z + Tv.z, 0.f));
    o.w = f2bf(fmaxf(acc3 * inv * Sv.w + Tv.w, 0.f));
    *(ushort4v*)(out + (size_t)node * F1 + j) = o;
}

// ---------------- layer-3 GEMM (N=16) + fused s3/d3 ----------------
__global__ __launch_bounds__(256) void gemm3_sd(const unsigned short* __restrict__ A, // [NN][256] bf16
                                                const float* __restrict__ W3,         // [256][16]
                                                const float* __restrict__ as3, const float* __restrict__ ad3,
                                                float* __restrict__ h3, float* __restrict__ s3, float* __restrict__ d3) {
    __shared__ __align__(16) float Ws[256 * 16];
    int tid = threadIdx.x;
    for (int p = tid; p < 1024; p += 256)
        ((float4*)Ws)[p] = ((const float4*)W3)[p];
    __syncthreads();
    int nl = tid >> 2;
    int q = tid & 3;
    int node = blockIdx.x * 64 + nl;
    float acc[16];
    for (int j = 0; j < 16; ++j) acc[j] = 0.f;
    if (node < NN) {
        const unsigned short* ar = A + (size_t)node * F1;
        for (int c = q; c < 32; c += 4) {
            short8 v8 = *(const short8*)(ar + c * 8);
            for (int u = 0; u < 8; ++u) {
                float av = bf2f((unsigned short)v8[u]);
                const float* wr = Ws + (c * 8 + u) * 16;
                float4 w0 = *(const float4*)(wr);
                float4 w1 = *(const float4*)(wr + 4);
                float4 w2 = *(const float4*)(wr + 8);
                float4 w3 = *(const float4*)(wr + 12);
                acc[0]  += av * w0.x; acc[1]  += av * w0.y; acc[2]  += av * w0.z; acc[3]  += av * w0.w;
                acc[4]  += av * w1.x; acc[5]  += av * w1.y; acc[6]  += av * w1.z; acc[7]  += av * w1.w;
                acc[8]  += av * w2.x; acc[9]  += av * w2.y; acc[10] += av * w2.z; acc[11] += av * w2.w;
                acc[12] += av * w3.x; acc[13] += av * w3.y; acc[14] += av * w3.z; acc[15] += av * w3.w;
            }
        }
    }
    for (int j = 0; j < 16; ++j) {
        acc[j] += __shfl_xor(acc[j], 1);
        acc[j] += __shfl_xor(acc[j], 2);
    }
    if (q == 0 && node < NN) {
        float sv = 0.f, dvv = 0.f;
        for (int j = 0; j < 16; ++j) {
            h3[(size_t)node * 16 + j] = acc[j];
            sv += acc[j] * as3[j];
            dvv += acc[j] * ad3[j];
        }
        s3[node] = sv;
        d3[node] = dvv;
    }
}

// ---------------- layer-3 aggregation (H=1, C=16) -> d_out ----------------
// lanes = 4 edge-slots x 16 channels
__global__ __launch_bounds__(256) void agg3(const float* __restrict__ h3, const float* __restrict__ s3,
                                            const float* __restrict__ d3, const int* __restrict__ rowptr,
                                            const int* __restrict__ csr, const float* __restrict__ b3,
                                            float* __restrict__ out) {
    int lane = threadIdx.x & 63;
    int node = blockIdx.x * 4 + (threadIdx.x >> 6);
    if (node >= NN) return;
    int r0 = rowptr[node], r1 = rowptr[node + 1];
    float dv = d3[node];
    int c = lane & 15, g = lane >> 4;
    float acc = 0.f, den = 0.f;
    for (int e = r0 + g; e < r1; e += 4) {
        int src = csr[e];
        float w = __expf(lrelu(s3[src] + dv));
        den += w;
        acc += w * h3[(size_t)src * 16 + c];
    }
    acc += __shfl_xor(acc, 16); acc += __shfl_xor(acc, 32);
    den += __shfl_xor(den, 16); den += __shfl_xor(den, 32);
    if (lane < 16) out[(size_t)node * 16 + lane] = acc / den + b3[lane];
}

// ---------------- host ----------------
extern "C" void kernel_launch(void* const* d_in, const int* in_sizes, int n_in,
                              void* d_out, int out_size, void* d_ws, size_t ws_size,
                              hipStream_t stream) {
    const float* x   = (const float*)d_in[0];
    const int*   ei  = (const int*)d_in[1];
    const float* W1  = (const float*)d_in[2];
    const float* as1 = (const float*)d_in[3];
    const float* ad1 = (const float*)d_in[4];
    const float* b1  = (const float*)d_in[5];
    const float* g1  = (const float*)d_in[6];
    const float* be1 = (const float*)d_in[7];
    const float* m1  = (const float*)d_in[8];
    const float* v1  = (const float*)d_in[9];
    const float* W2  = (const float*)d_in[10];
    const float* as2 = (const float*)d_in[11];
    const float* ad2 = (const float*)d_in[12];
    const float* b2  = (const float*)d_in[13];
    const float* g2  = (const float*)d_in[14];
    const float* be2 = (const float*)d_in[15];
    const float* m2  = (const float*)d_in[16];
    const float* v2  = (const float*)d_in[17];
    const float* W3  = (const float*)d_in[18];
    const float* as3 = (const float*)d_in[19];
    const float* ad3 = (const float*)d_in[20];
    const float* b3  = (const float*)d_in[21];

    char* w = (char*)d_ws;
    size_t off = 0;
    auto alloc = [&](size_t bytes) -> void* {
        off = (off + 255) & ~(size_t)255;
        void* p = w + off;
        off += bytes;
        return p;
    };
    unsigned short* xb   = (unsigned short*)alloc((size_t)NN * 128 * 2);
    unsigned short* W1t  = (unsigned short*)alloc(256 * 128 * 2);
    unsigned short* W2t  = (unsigned short*)alloc(256 * 256 * 2);
    unsigned short* Abuf = (unsigned short*)alloc((size_t)NN * F1 * 2);  // h1 / h2
    unsigned short* Bbuf = (unsigned short*)alloc((size_t)NN * F1 * 2);  // out1 / out2
    float* h3    = (float*)alloc((size_t)NN * 16 * 4);
    float* s_arr = (float*)alloc((size_t)NN * 4 * 4);
    float* d_arr = (float*)alloc((size_t)NN * 4 * 4);
    float* s3    = (float*)alloc((size_t)NN * 4);
    float* d3    = (float*)alloc((size_t)NN * 4);
    int* counts  = (int*)alloc((size_t)NN * 4);
    int* rowptr  = (int*)alloc((size_t)(NN + 1) * 4);
    int* cursor  = (int*)alloc((size_t)NN * 4);
    int* csr     = (int*)alloc((size_t)ET * 4);
    int* bsum    = (int*)alloc(256 * 4);
    float* S1 = (float*)alloc(F1 * 4);
    float* T1 = (float*)alloc(F1 * 4);
    float* S2 = (float*)alloc(F1 * 4);
    float* T2 = (float*)alloc(F1 * 4);
    float* outp = (float*)d_out;

    int nb_scan = (NN + 255) / 256;        // 196
    int nb_edge = (ET + 255) / 256;        // 3321

    // prep
    cast_f32_bf16<<<(NN * 128 / 4 + 255) / 256, 256, 0, stream>>>(x, xb, NN * 128 / 4);
    transpose_w<<<(128 * 256 + 255) / 256, 256, 0, stream>>>(W1, W1t, 128, 256);
    transpose_w<<<(256 * 256 + 255) / 256, 256, 0, stream>>>(W2, W2t, 256, 256);
    bn_prep<<<1, 256, 0, stream>>>(b1, g1, be1, m1, v1, S1, T1, F1);
    bn_prep<<<1, 256, 0, stream>>>(b2, g2, be2, m2, v2, S2, T2, F1);

    // CSR by dst
    hipMemsetAsync(counts, 0, (size_t)NN * 4, stream);
    edge_hist<<<nb_edge, 256, 0, stream>>>(ei, counts);
    scan_a<<<nb_scan, 256, 0, stream>>>(counts, rowptr, bsum);
    scan_b<<<1, 256, 0, stream>>>(bsum, nb_scan);
    scan_c<<<nb_scan, 256, 0, stream>>>(rowptr, bsum);
    copy_cursor<<<nb_scan, 256, 0, stream>>>(rowptr, cursor);
    edge_scatter<<<nb_edge, 256, 0, stream>>>(ei, cursor, csr);

    dim3 ggrid((NN + BM - 1) / BM, F1 / BN);

    // layer 1
    gemm_bf16<<<ggrid, 256, 0, stream>>>(xb, W1t, Abuf, NN, 128, F1);
    sd12<<<(NN + 3) / 4, 256, 0, stream>>>(Abuf, as1, ad1, s_arr, d_arr);
    agg12<<<(NN + 3) / 4, 256, 0, stream>>>(Abuf, s_arr, d_arr, rowptr, csr, S1, T1, Bbuf);

    // layer 2
    gemm_bf16<<<ggrid, 256, 0, stream>>>(Bbuf, W2t, Abuf, NN, 256, F1);
    sd12<<<(NN + 3) / 4, 256, 0, stream>>>(Abuf, as2, ad2, s_arr, d_arr);
    agg12<<<(NN + 3) / 4, 256, 0, stream>>>(Abuf, s_arr, d_arr, rowptr, csr, S2, T2, Bbuf);

    // layer 3
    gemm3_sd<<<(NN + 63) / 64, 256, 0, stream>>>(Bbuf, W3, as3, ad3, h3, s3, d3);
    agg3<<<(NN + 3) / 4, 256, 0, stream>>>(h3, s3, d3, rowptr, csr, b3, outp);
}

// Round 3
// 428.386 us; speedup vs baseline: 1.6027x; 1.1777x over previous
//
#include <hip/hip_runtime.h>
#include <math.h>

#define NN 50000
#define NE 800000
#define ET (NE + NN)          // edges + self loops
#define F1 256                // HEADS*HID
#define NEG 0.2f
#define BN_EPS 1e-5f

typedef __attribute__((ext_vector_type(8))) short short8;
typedef __attribute__((ext_vector_type(4))) float float4v;
typedef __attribute__((ext_vector_type(4))) unsigned short ushort4v;

__device__ __forceinline__ float bf2f(unsigned short u) {
    unsigned int x = ((unsigned int)u) << 16;
    return __builtin_bit_cast(float, x);
}
__device__ __forceinline__ unsigned short f2bf(float f) {
    unsigned int x = __builtin_bit_cast(unsigned int, f);
    unsigned int lsb = (x >> 16) & 1u;
    x += 0x7fffu + lsb;
    return (unsigned short)(x >> 16);
}
__device__ __forceinline__ float lrelu(float x) { return x > 0.f ? x : NEG * x; }

// ---------------- prep kernels ----------------
__global__ void cast_f32_bf16(const float* __restrict__ in, unsigned short* __restrict__ out, int n4) {
    int i = (blockIdx.x * 256 + threadIdx.x);
    if (i < n4) {
        float4 v = ((const float4*)in)[i];
        ushort4 o;
        o.x = f2bf(v.x); o.y = f2bf(v.y); o.z = f2bf(v.z); o.w = f2bf(v.w);
        ((ushort4*)out)[i] = o;
    }
}

// W [K][Nn] f32 -> Wt [Nn][K] bf16
__global__ void transpose_w(const float* __restrict__ W, unsigned short* __restrict__ Wt, int K, int Nn) {
    int id = blockIdx.x * 256 + threadIdx.x;
    if (id < K * Nn) {
        int n = id / K, k = id - n * K;
        Wt[id] = f2bf(W[k * Nn + n]);
    }
}

// fold bias+BN for both layers in one launch: y = relu(x*S + T)
__global__ void bn_prep2(const float* __restrict__ b1, const float* __restrict__ g1,
                         const float* __restrict__ be1, const float* __restrict__ m1,
                         const float* __restrict__ v1, float* __restrict__ S1, float* __restrict__ T1,
                         const float* __restrict__ b2, const float* __restrict__ g2,
                         const float* __restrict__ be2, const float* __restrict__ m2,
                         const float* __restrict__ v2, float* __restrict__ S2, float* __restrict__ T2) {
    int j = threadIdx.x;
    if (blockIdx.x == 0) {
        float s = g1[j] * rsqrtf(v1[j] + BN_EPS);
        S1[j] = s;
        T1[j] = (b1[j] - m1[j]) * s + be1[j];
    } else {
        float s = g2[j] * rsqrtf(v2[j] + BN_EPS);
        S2[j] = s;
        T2[j] = (b2[j] - m2[j]) * s + be2[j];
    }
}

// ---------------- CSR build (rank-based, single atomic pass) ----------------
__global__ void edge_hist_rank(const int* __restrict__ ei, int* __restrict__ counts, int* __restrict__ rank) {
    int e = blockIdx.x * 256 + threadIdx.x;
    if (e < ET) {
        int dst = (e < NE) ? ei[NE + e] : (e - NE);
        rank[e] = atomicAdd(&counts[dst], 1);
    }
}

__global__ void scan_a(const int* __restrict__ counts, int* __restrict__ rowptr, int* __restrict__ bsum) {
    __shared__ int s[256];
    int t = threadIdx.x, i = blockIdx.x * 256 + t;
    int v = (i < NN) ? counts[i] : 0;
    s[t] = v;
    __syncthreads();
    for (int off = 1; off < 256; off <<= 1) {
        int add = (t >= off) ? s[t - off] : 0;
        __syncthreads();
        s[t] += add;
        __syncthreads();
    }
    if (i < NN) rowptr[i + 1] = s[t];
    if (t == 255) bsum[blockIdx.x] = s[255];
}

// parallel exclusive scan over <=256 block sums
__global__ void scan_b(int* __restrict__ bsum, int nb) {
    __shared__ int s[256];
    int t = threadIdx.x;
    int v = (t < nb) ? bsum[t] : 0;
    s[t] = v;
    __syncthreads();
    for (int off = 1; off < 256; off <<= 1) {
        int add = (t >= off) ? s[t - off] : 0;
        __syncthreads();
        s[t] += add;
        __syncthreads();
    }
    if (t < nb) bsum[t] = s[t] - v;  // exclusive
}

__global__ void scan_c(int* __restrict__ rowptr, const int* __restrict__ bsum) {
    int i = blockIdx.x * 256 + threadIdx.x;
    if (i < NN) rowptr[i + 1] += bsum[i >> 8];
    if (i == 0) rowptr[0] = 0;
}

__global__ void edge_place(const int* __restrict__ ei, const int* __restrict__ rowptr,
                           const int* __restrict__ rank, int* __restrict__ csr) {
    int e = blockIdx.x * 256 + threadIdx.x;
    if (e < ET) {
        int src, dst;
        if (e < NE) { src = ei[e]; dst = ei[NE + e]; }
        else        { src = e - NE; dst = src; }
        csr[rowptr[dst] + rank[e]] = src;
    }
}

// ---------------- bf16 MFMA GEMM: C[M][Nn] = A[M][K] * Bt[Nn][K]^T ----------------
#define BM 128
#define BN 128
#define BK 64
#define LP 72  // BK + 8 pad

__global__ __launch_bounds__(256) void gemm_bf16(const unsigned short* __restrict__ A,
                                                 const unsigned short* __restrict__ Bt,
                                                 unsigned short* __restrict__ C,
                                                 int M, int K, int Nn) {
    __shared__ __align__(16) unsigned short As[BM * LP];
    __shared__ __align__(16) unsigned short Bs[BN * LP];
    int tid = threadIdx.x;
    int lane = tid & 63;
    int w = tid >> 6;
    int wr = w >> 1, wc = w & 1;
    int mBase = blockIdx.x * BM;
    int nBase = blockIdx.y * BN;

    float4v acc[4][4];
    for (int i = 0; i < 4; ++i)
        for (int j = 0; j < 4; ++j)
            acc[i][j] = (float4v){0.f, 0.f, 0.f, 0.f};

    int lm = lane & 15;
    int lk = (lane >> 4) * 8;

    for (int k0 = 0; k0 < K; k0 += BK) {
        for (int p = 0; p < 4; ++p) {
            int chunk = p * 256 + tid;
            int row = chunk >> 3;
            int c8 = (chunk & 7) * 8;
            int gm = mBase + row;
            short8 va = {0, 0, 0, 0, 0, 0, 0, 0};
            if (gm < M) va = *(const short8*)(A + (size_t)gm * K + k0 + c8);
            *(short8*)(&As[row * LP + c8]) = va;
            int gn = nBase + row;
            short8 vb = *(const short8*)(Bt + (size_t)gn * K + k0 + c8);
            *(short8*)(&Bs[row * LP + c8]) = vb;
        }
        __syncthreads();
        for (int ks = 0; ks < BK; ks += 32) {
            short8 af[4], bf[4];
            for (int i = 0; i < 4; ++i)
                af[i] = *(const short8*)(&As[(wr * 64 + i * 16 + lm) * LP + ks + lk]);
            for (int j = 0; j < 4; ++j)
                bf[j] = *(const short8*)(&Bs[(wc * 64 + j * 16 + lm) * LP + ks + lk]);
            for (int i = 0; i < 4; ++i)
                for (int j = 0; j < 4; ++j)
                    acc[i][j] = __builtin_amdgcn_mfma_f32_16x16x32_bf16(af[i], bf[j], acc[i][j], 0, 0, 0);
        }
        __syncthreads();
    }
    int lr = (lane >> 4) * 4;
    for (int i = 0; i < 4; ++i)
        for (int j = 0; j < 4; ++j) {
            int col = nBase + wc * 64 + j * 16 + lm;
            for (int r = 0; r < 4; ++r) {
                int row = mBase + wr * 64 + i * 16 + lr + r;
                if (row < M) C[(size_t)row * Nn + col] = f2bf(acc[i][j][r]);
            }
        }
}

// ---------------- s/d node coefficients, layers 1&2 (H=4, C=64) ----------------
__global__ __launch_bounds__(256) void sd12(const unsigned short* __restrict__ h,
                                            const float* __restrict__ a_s, const float* __restrict__ a_d,
                                            float* __restrict__ s_arr, float* __restrict__ d_arr) {
    int lane = threadIdx.x & 63;
    int node = blockIdx.x * 4 + (threadIdx.x >> 6);
    if (node >= NN) return;
    int j = lane * 4;   // 4 channels per lane; head = lane>>4
    ushort4v hv = *(const ushort4v*)(h + (size_t)node * F1 + j);
    float4 av = *(const float4*)(a_s + j);
    float4 dvv = *(const float4*)(a_d + j);
    float x0 = bf2f(hv.x), x1 = bf2f(hv.y), x2 = bf2f(hv.z), x3 = bf2f(hv.w);
    float sv = x0 * av.x + x1 * av.y + x2 * av.z + x3 * av.w;
    float dd = x0 * dvv.x + x1 * dvv.y + x2 * dvv.z + x3 * dvv.w;
    for (int off = 1; off < 16; off <<= 1) {
        sv += __shfl_xor(sv, off);
        dd += __shfl_xor(dd, off);
    }
    float s0 = __shfl(sv, 0), s1 = __shfl(sv, 16), s2 = __shfl(sv, 32), s3 = __shfl(sv, 48);
    float d0 = __shfl(dd, 0), d1 = __shfl(dd, 16), d2 = __shfl(dd, 32), d3 = __shfl(dd, 48);
    if (lane == 0) {
        *(float4*)(s_arr + node * 4) = make_float4(s0, s1, s2, s3);
        *(float4*)(d_arr + node * 4) = make_float4(d0, d1, d2, d3);
    }
}

// ---------------- fused softmax-attention aggregation, layers 1&2 ----------------
// one wave per dst node; per 64-edge chunk: lane e computes weights for edge e
// (staged to this wave's LDS slice), then a sweep processing TWO edges per
// iteration: lanes 0-31 = edge k (16B each), lanes 32-63 = edge k+1.
__global__ __launch_bounds__(256) void agg12(const unsigned short* __restrict__ h,
                                             const float* __restrict__ s_arr, const float* __restrict__ d_arr,
                                             const int* __restrict__ rowptr, const int* __restrict__ csr,
                                             const float* __restrict__ S, const float* __restrict__ T,
                                             unsigned short* __restrict__ out) {
    __shared__ float wls[4][64 * 5];   // per-wave: 64 edges x {w0,w1,w2,w3,src}
    int lane = threadIdx.x & 63;
    int wv = threadIdx.x >> 6;
    int node = blockIdx.x * 4 + wv;
    if (node >= NN) return;
    int r0 = rowptr[node], r1 = rowptr[node + 1];
    float4 dv = *(const float4*)(d_arr + node * 4);
    float* wbuf = &wls[wv][0];
    int lp = lane & 31;          // 8-channel group within row
    int half = lane >> 5;        // which of the 2 edges this iteration
    int head8 = lp >> 3;         // head of channels lp*8..lp*8+7
    const unsigned short* hbase = h + lp * 8;

    float acc[8] = {0.f, 0.f, 0.f, 0.f, 0.f, 0.f, 0.f, 0.f};
    float den0 = 0.f, den1 = 0.f, den2 = 0.f, den3 = 0.f;

    for (int base = r0; base < r1; base += 64) {
        int cnt = min(64, r1 - base);
        if (lane < cnt) {
            int src = csr[base + lane];
            float4 sv = *(const float4*)(s_arr + src * 4);
            float w0 = __expf(lrelu(sv.x + dv.x));
            float w1 = __expf(lrelu(sv.y + dv.y));
            float w2 = __expf(lrelu(sv.z + dv.z));
            float w3 = __expf(lrelu(sv.w + dv.w));
            den0 += w0; den1 += w1; den2 += w2; den3 += w3;
            float* wp = wbuf + lane * 5;
            wp[0] = w0; wp[1] = w1; wp[2] = w2; wp[3] = w3;
            wp[4] = __int_as_float(src);
        } else if (lane == cnt) {  // pad to even edge count
            float* wp = wbuf + lane * 5;
            wp[0] = 0.f; wp[1] = 0.f; wp[2] = 0.f; wp[3] = 0.f;
            wp[4] = __int_as_float(node);
        }
        int cpad = (cnt + 1) & ~1;
        for (int k = 0; k < cpad; k += 2) {
            int k2 = k + half;
            const float* wp = wbuf + k2 * 5;
            int src = __float_as_int(wp[4]);
            float wgt = wp[head8];
            short8 hv = *(const short8*)(hbase + src * F1);
            acc[0] += wgt * bf2f((unsigned short)hv[0]);
            acc[1] += wgt * bf2f((unsigned short)hv[1]);
            acc[2] += wgt * bf2f((unsigned short)hv[2]);
            acc[3] += wgt * bf2f((unsigned short)hv[3]);
            acc[4] += wgt * bf2f((unsigned short)hv[4]);
            acc[5] += wgt * bf2f((unsigned short)hv[5]);
            acc[6] += wgt * bf2f((unsigned short)hv[6]);
            acc[7] += wgt * bf2f((unsigned short)hv[7]);
        }
    }
    // combine the two halves (same channels, different edge parity)
    for (int u = 0; u < 8; ++u) acc[u] += __shfl_xor(acc[u], 32);
    // denominators (staged across all 64 lanes)
    for (int off = 32; off; off >>= 1) {
        den0 += __shfl_xor(den0, off);
        den1 += __shfl_xor(den1, off);
        den2 += __shfl_xor(den2, off);
        den3 += __shfl_xor(den3, off);
    }
    if (half == 0) {
        float den = (head8 == 0) ? den0 : (head8 == 1) ? den1 : (head8 == 2) ? den2 : den3;
        float inv = 1.f / den;
        int j = lp * 8;
        float4 Sv0 = *(const float4*)(S + j);
        float4 Sv1 = *(const float4*)(S + j + 4);
        float4 Tv0 = *(const float4*)(T + j);
        float4 Tv1 = *(const float4*)(T + j + 4);
        short8 o;
        o[0] = (short)f2bf(fmaxf(acc[0] * inv * Sv0.x + Tv0.x, 0.f));
        o[1] = (short)f2bf(fmaxf(acc[1] * inv * Sv0.y + Tv0.y, 0.f));
        o[2] = (short)f2bf(fmaxf(acc[2] * inv * Sv0.z + Tv0.z, 0.f));
        o[3] = (short)f2bf(fmaxf(acc[3] * inv * Sv0.w + Tv0.w, 0.f));
        o[4] = (short)f2bf(fmaxf(acc[4] * inv * Sv1.x + Tv1.x, 0.f));
        o[5] = (short)f2bf(fmaxf(acc[5] * inv * Sv1.y + Tv1.y, 0.f));
        o[6] = (short)f2bf(fmaxf(acc[6] * inv * Sv1.z + Tv1.z, 0.f));
        o[7] = (short)f2bf(fmaxf(acc[7] * inv * Sv1.w + Tv1.w, 0.f));
        *(short8*)(out + (size_t)node * F1 + j) = o;
    }
}

// ---------------- layer-3 GEMM (N=16) + fused s3/d3 ----------------
__global__ __launch_bounds__(256) void gemm3_sd(const unsigned short* __restrict__ A, // [NN][256] bf16
                                                const float* __restrict__ W3,         // [256][16]
                                                const float* __restrict__ as3, const float* __restrict__ ad3,
                                                float* __restrict__ h3, float* __restrict__ s3, float* __restrict__ d3) {
    __shared__ __align__(16) float Ws[256 * 16];
    int tid = threadIdx.x;
    for (int p = tid; p < 1024; p += 256)
        ((float4*)Ws)[p] = ((const float4*)W3)[p];
    __syncthreads();
    int nl = tid >> 2;
    int q = tid & 3;
    int node = blockIdx.x * 64 + nl;
    float acc[16];
    for (int j = 0; j < 16; ++j) acc[j] = 0.f;
    if (node < NN) {
        const unsigned short* ar = A + (size_t)node * F1;
        for (int c = q; c < 32; c += 4) {
            short8 v8 = *(const short8*)(ar + c * 8);
            for (int u = 0; u < 8; ++u) {
                float av = bf2f((unsigned short)v8[u]);
                const float* wr = Ws + (c * 8 + u) * 16;
                float4 w0 = *(const float4*)(wr);
                float4 w1 = *(const float4*)(wr + 4);
                float4 w2 = *(const float4*)(wr + 8);
                float4 w3 = *(const float4*)(wr + 12);
                acc[0]  += av * w0.x; acc[1]  += av * w0.y; acc[2]  += av * w0.z; acc[3]  += av * w0.w;
                acc[4]  += av * w1.x; acc[5]  += av * w1.y; acc[6]  += av * w1.z; acc[7]  += av * w1.w;
                acc[8]  += av * w2.x; acc[9]  += av * w2.y; acc[10] += av * w2.z; acc[11] += av * w2.w;
                acc[12] += av * w3.x; acc[13] += av * w3.y; acc[14] += av * w3.z; acc[15] += av * w3.w;
            }
        }
    }
    for (int j = 0; j < 16; ++j) {
        acc[j] += __shfl_xor(acc[j], 1);
        acc[j] += __shfl_xor(acc[j], 2);
    }
    if (q == 0 && node < NN) {
        float sv = 0.f, dvv = 0.f;
        for (int j = 0; j < 16; ++j) {
            h3[(size_t)node * 16 + j] = acc[j];
            sv += acc[j] * as3[j];
            dvv += acc[j] * ad3[j];
        }
        s3[node] = sv;
        d3[node] = dvv;
    }
}

// ---------------- layer-3 aggregation (H=1, C=16) -> d_out ----------------
__global__ __launch_bounds__(256) void agg3(const float* __restrict__ h3, const float* __restrict__ s3,
                                            const float* __restrict__ d3, const int* __restrict__ rowptr,
                                            const int* __restrict__ csr, const float* __restrict__ b3,
                                            float* __restrict__ out) {
    int lane = threadIdx.x & 63;
    int node = blockIdx.x * 4 + (threadIdx.x >> 6);
    if (node >= NN) return;
    int r0 = rowptr[node], r1 = rowptr[node + 1];
    float dv = d3[node];
    int c = lane & 15, g = lane >> 4;
    float acc = 0.f, den = 0.f;
    for (int e = r0 + g; e < r1; e += 4) {
        int src = csr[e];
        float w = __expf(lrelu(s3[src] + dv));
        den += w;
        acc += w * h3[(size_t)src * 16 + c];
    }
    acc += __shfl_xor(acc, 16); acc += __shfl_xor(acc, 32);
    den += __shfl_xor(den, 16); den += __shfl_xor(den, 32);
    if (lane < 16) out[(size_t)node * 16 + lane] = acc / den + b3[lane];
}

// ---------------- host ----------------
extern "C" void kernel_launch(void* const* d_in, const int* in_sizes, int n_in,
                              void* d_out, int out_size, void* d_ws, size_t ws_size,
                              hipStream_t stream) {
    const float* x   = (const float*)d_in[0];
    const int*   ei  = (const int*)d_in[1];
    const float* W1  = (const float*)d_in[2];
    const float* as1 = (const float*)d_in[3];
    const float* ad1 = (const float*)d_in[4];
    const float* b1  = (const float*)d_in[5];
    const float* g1  = (const float*)d_in[6];
    const float* be1 = (const float*)d_in[7];
    const float* m1  = (const float*)d_in[8];
    const float* v1  = (const float*)d_in[9];
    const float* W2  = (const float*)d_in[10];
    const float* as2 = (const float*)d_in[11];
    const float* ad2 = (const float*)d_in[12];
    const float* b2  = (const float*)d_in[13];
    const float* g2  = (const float*)d_in[14];
    const float* be2 = (const float*)d_in[15];
    const float* m2  = (const float*)d_in[16];
    const float* v2  = (const float*)d_in[17];
    const float* W3  = (const float*)d_in[18];
    const float* as3 = (const float*)d_in[19];
    const float* ad3 = (const float*)d_in[20];
    const float* b3  = (const float*)d_in[21];

    char* w = (char*)d_ws;
    size_t off = 0;
    auto alloc = [&](size_t bytes) -> void* {
        off = (off + 255) & ~(size_t)255;
        void* p = w + off;
        off += bytes;
        return p;
    };
    unsigned short* xb   = (unsigned short*)alloc((size_t)NN * 128 * 2);
    unsigned short* W1t  = (unsigned short*)alloc(256 * 128 * 2);
    unsigned short* W2t  = (unsigned short*)alloc(256 * 256 * 2);
    unsigned short* Abuf = (unsigned short*)alloc((size_t)NN * F1 * 2);  // h1 / h2
    unsigned short* Bbuf = (unsigned short*)alloc((size_t)NN * F1 * 2);  // out1 / out2
    float* h3    = (float*)alloc((size_t)NN * 16 * 4);
    float* s_arr = (float*)alloc((size_t)NN * 4 * 4);
    float* d_arr = (float*)alloc((size_t)NN * 4 * 4);
    float* s3    = (float*)alloc((size_t)NN * 4);
    float* d3    = (float*)alloc((size_t)NN * 4);
    int* counts  = (int*)alloc((size_t)NN * 4);
    int* rowptr  = (int*)alloc((size_t)(NN + 1) * 4);
    int* rank    = (int*)alloc((size_t)ET * 4);
    int* csr     = (int*)alloc((size_t)ET * 4);
    int* bsum    = (int*)alloc(256 * 4);
    float* S1 = (float*)alloc(F1 * 4);
    float* T1 = (float*)alloc(F1 * 4);
    float* S2 = (float*)alloc(F1 * 4);
    float* T2 = (float*)alloc(F1 * 4);
    float* outp = (float*)d_out;

    int nb_scan = (NN + 255) / 256;        // 196
    int nb_edge = (ET + 255) / 256;        // 3321

    // prep
    cast_f32_bf16<<<(NN * 128 / 4 + 255) / 256, 256, 0, stream>>>(x, xb, NN * 128 / 4);
    transpose_w<<<(128 * 256 + 255) / 256, 256, 0, stream>>>(W1, W1t, 128, 256);
    transpose_w<<<(256 * 256 + 255) / 256, 256, 0, stream>>>(W2, W2t, 256, 256);
    bn_prep2<<<2, 256, 0, stream>>>(b1, g1, be1, m1, v1, S1, T1, b2, g2, be2, m2, v2, S2, T2);

    // CSR by dst (rank-based)
    hipMemsetAsync(counts, 0, (size_t)NN * 4, stream);
    edge_hist_rank<<<nb_edge, 256, 0, stream>>>(ei, counts, rank);
    scan_a<<<nb_scan, 256, 0, stream>>>(counts, rowptr, bsum);
    scan_b<<<1, 256, 0, stream>>>(bsum, nb_scan);
    scan_c<<<nb_scan, 256, 0, stream>>>(rowptr, bsum);
    edge_place<<<nb_edge, 256, 0, stream>>>(ei, rowptr, rank, csr);

    dim3 ggrid((NN + BM - 1) / BM, F1 / BN);

    // layer 1
    gemm_bf16<<<ggrid, 256, 0, stream>>>(xb, W1t, Abuf, NN, 128, F1);
    sd12<<<(NN + 3) / 4, 256, 0, stream>>>(Abuf, as1, ad1, s_arr, d_arr);
    agg12<<<(NN + 3) / 4, 256, 0, stream>>>(Abuf, s_arr, d_arr, rowptr, csr, S1, T1, Bbuf);

    // layer 2
    gemm_bf16<<<ggrid, 256, 0, stream>>>(Bbuf, W2t, Abuf, NN, 256, F1);
    sd12<<<(NN + 3) / 4, 256, 0, stream>>>(Abuf, as2, ad2, s_arr, d_arr);
    agg12<<<(NN + 3) / 4, 256, 0, stream>>>(Abuf, s_arr, d_arr, rowptr, csr, S2, T2, Bbuf);

    // layer 3
    gemm3_sd<<<(NN + 63) / 64, 256, 0, stream>>>(Bbuf, W3, as3, ad3, h3, s3, d3);
    agg3<<<(NN + 3) / 4, 256, 0, stream>>>(h3, s3, d3, rowptr, csr, b3, outp);
}